// Round 5
// baseline (6988.803 us; speedup 1.0000x reference)
//
#include <hip/hip_runtime.h>
#include <stdint.h>
#include <stddef.h>

// ---------------------------------------------------------------------------
// PCgraph: T=32 steps of
//   mu   = tanh(x) @ w^T     (only cols n>=784 of mu are ever used)
//   e    = (x - mu) * m      (e[:, :784] == 0)
//   g    = e @ w             (rows k<784 of w dead; cols n<784 of g dead)
//   x    = x - 0.1 * m * (e - (1-tanh(x)^2) * g)
// bf16 MFMA (16x16x32), fp32 accum. x state lives in d_out (fp32).
// Round 5: register-staged pipeline, HAND-UNROLLED x4 so every register-set
// index is a literal. Round 4's #pragma unroll left set indices runtime ->
// rA/rB lowered to scratch (VGPR_Count 56, WRITE_SIZE 70 MB = spill traffic).
// Pipeline: gload chunk kt+3 -> VGPR set (kt+3)&3; swrite chunk kt+1 from its
// set into LDS buf (kt+1)&1 (compiler emits precise vmcnt(4)); compute chunk
// kt from buf kt&1; s_waitcnt lgkmcnt(0) + raw s_barrier (NOT __syncthreads:
// its vmcnt(0) would drain the in-flight loads -- the round-2/3 disease).
// ws footprint: 55.1 MiB (round-1 failure was OOB ws writes).
// ---------------------------------------------------------------------------

#define N_DIM 4096
#define B_DIM 256
#define T_STEPS 32
#define LR_X 0.1f
#define N0 768                      // first live column (aligned down from 784)
#define N_LIVE 3328                 // 4096 - 768, = 52 * 64

#define BM 64
#define BN 64
#define BK 64

typedef unsigned short ushort_t;
using bf16x8 = __attribute__((ext_vector_type(8))) __bf16;
using f32x4  = __attribute__((ext_vector_type(4))) float;

__device__ __forceinline__ ushort_t f2bf(float f) {
    union { float f; unsigned int u; } v; v.f = f;
    unsigned int r = v.u + 0x7fffu + ((v.u >> 16) & 1u);   // RNE
    return (ushort_t)(r >> 16);
}

// s_waitcnt lgkmcnt(0), vmcnt/expcnt unconstrained.
// gfx9 simm16: vmcnt[3:0]=bits0-3, expcnt=bits4-6, lgkmcnt=bits8-11,
// vmcnt[5:4]=bits14-15  ->  vm=63, exp=7, lgkm=0  =>  0xC07F
#define WAIT_LGKM0() __builtin_amdgcn_s_waitcnt(0xC07F)

// --- w fp32 -> w_b bf16 [3328 x 4096] (rows 768..4095 of w)
//             + wt_b bf16 [3328 x 3328] (wt_b[n-768][k-768] = w[k][n]) --------
__global__ void convert_w(const float* __restrict__ w,
                          ushort_t* __restrict__ wb,
                          ushort_t* __restrict__ wtb) {
    __shared__ float tile[32][33];
    const int tx  = threadIdx.x & 31;
    const int ty  = threadIdx.x >> 5;            // 0..7
    const int bx  = blockIdx.x;                  // col tile over [0,4096)
    const int by  = blockIdx.y;                  // row tile over [768,4096)
#pragma unroll
    for (int rr = 0; rr < 32; rr += 8) {
        int rloc = by * 32 + rr + ty;            // row in w_b
        int c    = bx * 32 + tx;
        float v = w[(size_t)(N0 + rloc) * N_DIM + c];
        wb[(size_t)rloc * N_DIM + c] = f2bf(v);
        tile[rr + ty][tx] = v;
    }
    __syncthreads();
    if (bx >= N0 / 32) {                         // cols >= 768 also go to wt_b
#pragma unroll
        for (int rr = 0; rr < 32; rr += 8) {
            int r = bx * 32 - N0 + rr + ty;      // wt row = c_w - 768
            int c = by * 32 + tx;                // wt col = r_w - 768
            wtb[(size_t)r * N_LIVE + c] = f2bf(tile[tx][rr + ty]);
        }
    }
}

// --- x init: copy x into d_out, t = tanh(x) in bf16 -------------------------
__global__ void init_x(const float* __restrict__ xin,
                       float* __restrict__ xout,
                       ushort_t* __restrict__ tb) {
    int i = blockIdx.x * 256 + threadIdx.x;
    float v = xin[i];
    xout[i] = v;
    tb[i]   = f2bf(tanhf(v));
}

// --- fused GEMM + epilogue --------------------------------------------------
// C[m][n] = sum_k A[m][k] * B[nloc][kloc],  n = 768 + nloc, kloc = k - KSTART
// A: [256][4096] bf16 (k absolute). B: [3328][BSTR] bf16.
// PHASE 1: C = mu;  e = (x - mu)*mask  -> e_f32, e_bf16
// PHASE 2: C = g;   x -= LR*mask*(e - (1-tanh(x)^2)*g); t = tanh(x_new) bf16
template <int PHASE, int BSTR, int KSTART, int NKT>
__global__ __launch_bounds__(256) void gemm_step(
    const ushort_t* __restrict__ Amat,
    const ushort_t* __restrict__ Bmat,
    const float* xbuf,                 // no restrict: aliases xout in PHASE 2
    float* xout,
    const float* __restrict__ ef32_in,
    float* __restrict__ ef32_out,
    ushort_t* __restrict__ ebf16,
    ushort_t* __restrict__ tbf16,
    const int* __restrict__ mask) {
    static_assert(NKT % 4 == 0, "pipeline tail assumes NKT % 4 == 0");
    // Fragment-order LDS: sub-tile s (msub = s>>1, ksub = s&1) occupies
    // 512 elements; staging lane L writes exactly the 16B that compute-lane L
    // reads -> ds_write_b128 / ds_read_b128 both lane-consecutive, 0 conflicts.
    __shared__ __align__(16) ushort_t As[2][BM * BK];
    __shared__ __align__(16) ushort_t Bs[2][BN * BK];

    const int tid    = threadIdx.x;
    const int lane   = tid & 63;
    const int wid    = tid >> 6;       // 0..3
    const int wave_m = wid >> 1;       // 0..1
    const int wave_n = wid & 1;        // 0..1
    const int n0loc = blockIdx.x * BN; // local col in live range
    const int m0    = blockIdx.y * BM;

    const int l15  = lane & 15;
    const int quad = lane >> 4;        // 0..3

    // Per-thread source pointers + LDS offsets for its two sub-tiles.
    const ushort_t* aptr[2];
    const ushort_t* bptr[2];
    int lofs[2];
#pragma unroll
    for (int u = 0; u < 2; ++u) {
        const int s   = wid * 2 + u;           // sub-tile id 0..7
        const int row = (s >> 1) * 16 + l15;   // m (or n) within tile
        const int kk  = (s & 1) * 32 + (quad << 3);
        aptr[u] = Amat + (size_t)(m0 + row) * N_DIM + KSTART + kk;
        bptr[u] = Bmat + (size_t)(n0loc + row) * BSTR + kk;
        lofs[u] = s * 512 + lane * 8;
    }

    // 4 register sets; ALL indices below are literals (no scratch lowering).
    uint4 rA[4][2], rB[4][2];

    // set must be a literal at each call site.
#define GLOAD(set, kt)                                                   \
    do {                                                                 \
        rA[set][0] = *(const uint4*)(aptr[0] + (size_t)(kt) * BK);       \
        rA[set][1] = *(const uint4*)(aptr[1] + (size_t)(kt) * BK);       \
        rB[set][0] = *(const uint4*)(bptr[0] + (size_t)(kt) * BK);       \
        rB[set][1] = *(const uint4*)(bptr[1] + (size_t)(kt) * BK);       \
    } while (0)
#define SWRITE(set, buf)                                                 \
    do {                                                                 \
        *(uint4*)&As[buf][lofs[0]] = rA[set][0];                         \
        *(uint4*)&As[buf][lofs[1]] = rA[set][1];                         \
        *(uint4*)&Bs[buf][lofs[0]] = rB[set][0];                         \
        *(uint4*)&Bs[buf][lofs[1]] = rB[set][1];                         \
    } while (0)

    f32x4 acc[2][2] = {};

    auto compute = [&](int buf) {
#pragma unroll
        for (int ks = 0; ks < 2; ++ks) {
            bf16x8 a[2], b[2];
#pragma unroll
            for (int i = 0; i < 2; ++i) {
                const int asub = (wave_m * 2 + i) * 2 + ks;
                const int bsub = (wave_n * 2 + i) * 2 + ks;
                a[i] = *(const bf16x8*)(&As[buf][asub * 512 + lane * 8]);
                b[i] = *(const bf16x8*)(&Bs[buf][bsub * 512 + lane * 8]);
            }
#pragma unroll
            for (int i = 0; i < 2; ++i)
#pragma unroll
                for (int j = 0; j < 2; ++j)
                    acc[i][j] = __builtin_amdgcn_mfma_f32_16x16x32_bf16(
                        a[i], b[j], acc[i][j], 0, 0, 0);
        }
    };

    // One pipeline step at kt = base + I (base % 4 == 0, I literal):
    //   publish chunk kt+1 (regs loaded 2 iters ago -> compiler vmcnt(4)),
    //   issue chunk kt+3, compute chunk kt, publish LDS via lgkm0+barrier.
#define STEP(I, kt, DO_W, DO_G)                                          \
    do {                                                                 \
        if (DO_W) SWRITE(((I) + 1) & 3, ((I) + 1) & 1);                  \
        if (DO_G) GLOAD(((I) + 3) & 3, (kt) + 3);                        \
        compute((I) & 1);                                                \
        WAIT_LGKM0();                                                    \
        __builtin_amdgcn_s_barrier();                                    \
    } while (0)

    // Prologue: chunks 0,1,2 in flight; publish chunk 0.
    GLOAD(0, 0); GLOAD(1, 1); GLOAD(2, 2);
    SWRITE(0, 0);                       // waits vmcnt for set-0 loads only
    WAIT_LGKM0();
    __builtin_amdgcn_s_barrier();

    for (int base = 0; base + 8 <= NKT; base += 4) {
        STEP(0, base + 0, 1, 1);
        STEP(1, base + 1, 1, 1);
        STEP(2, base + 2, 1, 1);
        STEP(3, base + 3, 1, 1);
    }
    // Tail block: base = NKT-4 (literal via template NKT).
    STEP(0, NKT - 4, 1, 1);             // gload chunk NKT-1 into set 3
    STEP(1, NKT - 3, 1, 0);
    STEP(2, NKT - 2, 1, 0);
    STEP(3, NKT - 1, 0, 0);

#undef STEP
#undef GLOAD
#undef SWRITE

    // Epilogue. C/D layout (verified m89/m91): col = lane&15, row = quad*4+reg
#pragma unroll
    for (int j = 0; j < 2; ++j) {
        const int n = N0 + n0loc + wave_n * 32 + j * 16 + l15;
        const float mval = (float)mask[n];
#pragma unroll
        for (int i = 0; i < 2; ++i) {
#pragma unroll
            for (int r = 0; r < 4; ++r) {
                const int m = m0 + wave_m * 32 + i * 16 + quad * 4 + r;
                const size_t idx = (size_t)m * N_DIM + n;
                const float v = acc[i][j][r];
                if (PHASE == 1) {
                    float e = (xbuf[idx] - v) * mval;
                    ef32_out[idx] = e;
                    ebf16[idx]    = f2bf(e);
                } else {
                    float xv   = xbuf[idx];
                    float th   = tanhf(xv);
                    float dEdx = ef32_in[idx] - (1.0f - th * th) * v;
                    float xn   = xv - LR_X * mval * dEdx;
                    xout[idx]  = xn;
                    tbf16[idx] = f2bf(tanhf(xn));
                }
            }
        }
    }
}

extern "C" void kernel_launch(void* const* d_in, const int* in_sizes, int n_in,
                              void* d_out, int out_size, void* d_ws, size_t ws_size,
                              hipStream_t stream) {
    const float* x_in  = (const float*)d_in[0];
    const float* w_in  = (const float*)d_in[1];
    const int*   mask  = (const int*)d_in[2];
    float*       xbuf  = (float*)d_out;          // state lives in d_out

    uint8_t* ws = (uint8_t*)d_ws;
    // ws layout (55.1 MiB total):
    ushort_t* w_b  = (ushort_t*)(ws);                    // 3328x4096 bf16 = 26 MiB
    ushort_t* wt_b = (ushort_t*)(ws + 27262976);         // 3328x3328 bf16 = 21.1 MiB
    ushort_t* t_b  = (ushort_t*)(ws + 49414144);         // 256x4096 bf16 = 2 MiB
    ushort_t* e_b  = (ushort_t*)(ws + 51511296);         // 256x4096 bf16 = 2 MiB
    float*    e_f  = (float*)   (ws + 53608448);         // 256x4096 f32  = 4 MiB
    // end @ 57802752 bytes

    convert_w<<<dim3(N_DIM / 32, N_LIVE / 32), 256, 0, stream>>>(w_in, w_b, wt_b);
    init_x<<<dim3((B_DIM * N_DIM) / 256), 256, 0, stream>>>(x_in, xbuf, t_b);

    for (int t = 0; t < T_STEPS; ++t) {
        // GEMM1: mu over live cols; A = tanh(x) [k: 0..4096), B = w_b
        gemm_step<1, N_DIM, 0, N_DIM / BK>
            <<<dim3(N_LIVE / BN, B_DIM / BM), 256, 0, stream>>>(
            t_b, w_b, xbuf, nullptr, nullptr, e_f, e_b, nullptr, mask);
        // GEMM2: g over live cols; A = e [k: 768..4096), B = wt_b
        gemm_step<2, N_LIVE, N0, N_LIVE / BK>
            <<<dim3(N_LIVE / BN, B_DIM / BM), 256, 0, stream>>>(
            e_b, wt_b, xbuf, xbuf, e_f, nullptr, nullptr, t_b, mask);
    }
}

// Round 6
// 2886.942 us; speedup vs baseline: 2.4208x; 2.4208x over previous
//
#include <hip/hip_runtime.h>
#include <stdint.h>
#include <stddef.h>

// ---------------------------------------------------------------------------
// PCgraph: T=32 steps of
//   mu   = tanh(x) @ w^T     (only cols n>=784 of mu are ever used)
//   e    = (x - mu) * m      (e[:, :784] == 0)
//   g    = e @ w             (rows k<784 of w dead; cols n<784 of g dead)
//   x    = x - 0.1 * m * (e - (1-tanh(x)^2) * g)
// bf16 MFMA (16x16x32), fp32 accum. x state lives in d_out (fp32).
// Round 6: BK=256 fat-chunk K-loop (16/13 iters instead of 64/52). Rounds 4/5
// proved register staging always spills (compiler won't SROA staging arrays);
// rounds 2/3 proved the __syncthreads drain costs ~2000 cyc/iter regardless
// of manual vmcnt. Since per-iter drain cost is ~constant (latency, not BW:
// 675 GB/s HBM, 3.4 TB/s L2 at 62 us -- no tier saturated), cut iteration
// count 4x and deepen MLP 4x (16 outstanding global_load_lds per thread).
// LDS 128 KB double-buffer, 1 block/CU, grid 208 fully resident.
// ws footprint: 55.1 MiB (round-1 failure was OOB ws writes).
// ---------------------------------------------------------------------------

#define N_DIM 4096
#define B_DIM 256
#define T_STEPS 32
#define LR_X 0.1f
#define N0 768                      // first live column (aligned down from 784)
#define N_LIVE 3328                 // 4096 - 768, = 52 * 64 = 13 * 256

#define BM 64
#define BN 64
#define BK 256                      // 8 k-subtiles of 32

typedef unsigned short ushort_t;
using bf16x8 = __attribute__((ext_vector_type(8))) __bf16;
using f32x4  = __attribute__((ext_vector_type(4))) float;

__device__ __forceinline__ ushort_t f2bf(float f) {
    union { float f; unsigned int u; } v; v.f = f;
    unsigned int r = v.u + 0x7fffu + ((v.u >> 16) & 1u);   // RNE
    return (ushort_t)(r >> 16);
}

__device__ __forceinline__ void async_copy16(const ushort_t* g, ushort_t* l) {
    __builtin_amdgcn_global_load_lds(
        (__attribute__((address_space(1))) void*)(g),
        (__attribute__((address_space(3))) void*)(l),
        16, 0, 0);
}

// --- w fp32 -> w_b bf16 [3328 x 4096] (rows 768..4095 of w)
//             + wt_b bf16 [3328 x 3328] (wt_b[n-768][k-768] = w[k][n]) --------
__global__ void convert_w(const float* __restrict__ w,
                          ushort_t* __restrict__ wb,
                          ushort_t* __restrict__ wtb) {
    __shared__ float tile[32][33];
    const int tx  = threadIdx.x & 31;
    const int ty  = threadIdx.x >> 5;            // 0..7
    const int bx  = blockIdx.x;                  // col tile over [0,4096)
    const int by  = blockIdx.y;                  // row tile over [768,4096)
#pragma unroll
    for (int rr = 0; rr < 32; rr += 8) {
        int rloc = by * 32 + rr + ty;            // row in w_b
        int c    = bx * 32 + tx;
        float v = w[(size_t)(N0 + rloc) * N_DIM + c];
        wb[(size_t)rloc * N_DIM + c] = f2bf(v);
        tile[rr + ty][tx] = v;
    }
    __syncthreads();
    if (bx >= N0 / 32) {                         // cols >= 768 also go to wt_b
#pragma unroll
        for (int rr = 0; rr < 32; rr += 8) {
            int r = bx * 32 - N0 + rr + ty;      // wt row = c_w - 768
            int c = by * 32 + tx;                // wt col = r_w - 768
            wtb[(size_t)r * N_LIVE + c] = f2bf(tile[tx][rr + ty]);
        }
    }
}

// --- x init: copy x into d_out, t = tanh(x) in bf16 -------------------------
__global__ void init_x(const float* __restrict__ xin,
                       float* __restrict__ xout,
                       ushort_t* __restrict__ tb) {
    int i = blockIdx.x * 256 + threadIdx.x;
    float v = xin[i];
    xout[i] = v;
    tb[i]   = f2bf(tanhf(v));
}

// --- fused GEMM + epilogue --------------------------------------------------
// C[m][n] = sum_k A[m][k] * B[nloc][kloc],  n = 768 + nloc, kloc = k - KSTART
// A: [256][4096] bf16 (k absolute). B: [3328][BSTR] bf16.
// PHASE 1: C = mu;  e = (x - mu)*mask  -> e_f32, e_bf16
// PHASE 2: C = g;   x -= LR*mask*(e - (1-tanh(x)^2)*g); t = tanh(x_new) bf16
template <int PHASE, int BSTR, int KSTART, int NKT>
__global__ __launch_bounds__(256) void gemm_step(
    const ushort_t* __restrict__ Amat,
    const ushort_t* __restrict__ Bmat,
    const float* xbuf,                 // no restrict: aliases xout in PHASE 2
    float* xout,
    const float* __restrict__ ef32_in,
    float* __restrict__ ef32_out,
    ushort_t* __restrict__ ebf16,
    ushort_t* __restrict__ tbf16,
    const int* __restrict__ mask) {
    // Fragment-order LDS: sub-tile (msub, ksub) = 16 rows x 32 k = 512 elem;
    // A sub-tile id sA = msub*8 + ksub; staging lane L writes exactly the 16B
    // compute-lane L reads -> conflict-free, and satisfies global_load_lds's
    // wave-uniform-base + lane*16 requirement.
    __shared__ __align__(16) ushort_t As[2][BM * BK];   // 2 x 32 KB
    __shared__ __align__(16) ushort_t Bs[2][BN * BK];   // 2 x 32 KB

    const int tid    = threadIdx.x;
    const int lane   = tid & 63;
    const int wid    = tid >> 6;       // 0..3
    const int wave_m = wid >> 1;       // 0..1
    const int wave_n = wid & 1;        // 0..1
    const int n0loc = blockIdx.x * BN; // local col in live range
    const int m0    = blockIdx.y * BM;

    const int l15  = lane & 15;
    const int quad = lane >> 4;        // 0..3

    // Wave w stages m-rows [16w, 16w+16) of A and n-rows [16w, 16w+16) of B,
    // all 8 k-subtiles: 16 copies/thread/iter (deep MLP).
    const ushort_t* arow = Amat + (size_t)(m0 + wid * 16 + l15) * N_DIM + KSTART
                         + (quad << 3);
    const ushort_t* brow = Bmat + (size_t)(n0loc + wid * 16 + l15) * BSTR
                         + (quad << 3);

    auto stage = [&](int buf, int kt) {
        const int kofs = kt * BK;
#pragma unroll
        for (int u = 0; u < 8; ++u) {
            const int dst = (wid * 8 + u) * 512 + lane * 8;
            async_copy16(arow + kofs + u * 32, &As[buf][dst]);
            async_copy16(brow + kofs + u * 32, &Bs[buf][dst]);
        }
    };

    f32x4 acc[2][2] = {};

    auto compute = [&](int buf) {
#pragma unroll
        for (int ks = 0; ks < 8; ++ks) {
            bf16x8 a[2], b[2];
#pragma unroll
            for (int i = 0; i < 2; ++i) {
                const int asub = (wave_m * 2 + i) * 8 + ks;
                const int bsub = (wave_n * 2 + i) * 8 + ks;
                a[i] = *(const bf16x8*)(&As[buf][asub * 512 + lane * 8]);
                b[i] = *(const bf16x8*)(&Bs[buf][bsub * 512 + lane * 8]);
            }
#pragma unroll
            for (int i = 0; i < 2; ++i)
#pragma unroll
                for (int j = 0; j < 2; ++j)
                    acc[i][j] = __builtin_amdgcn_mfma_f32_16x16x32_bf16(
                        a[i], b[j], acc[i][j], 0, 0, 0);
        }
    };

    stage(0, 0);
    __syncthreads();
    for (int kt = 0; kt < NKT; ++kt) {
        if (kt + 1 < NKT) stage((kt + 1) & 1, kt + 1);
        compute(kt & 1);
        __syncthreads();   // drains prefetch vmcnt + protects LDS reuse
    }

    // Epilogue. C/D layout (verified m89/m91): col = lane&15, row = quad*4+reg
#pragma unroll
    for (int j = 0; j < 2; ++j) {
        const int n = N0 + n0loc + wave_n * 32 + j * 16 + l15;
        const float mval = (float)mask[n];
#pragma unroll
        for (int i = 0; i < 2; ++i) {
#pragma unroll
            for (int r = 0; r < 4; ++r) {
                const int m = m0 + wave_m * 32 + i * 16 + quad * 4 + r;
                const size_t idx = (size_t)m * N_DIM + n;
                const float v = acc[i][j][r];
                if (PHASE == 1) {
                    float e = (xbuf[idx] - v) * mval;
                    ef32_out[idx] = e;
                    ebf16[idx]    = f2bf(e);
                } else {
                    float xv   = xbuf[idx];
                    float th   = tanhf(xv);
                    float dEdx = ef32_in[idx] - (1.0f - th * th) * v;
                    float xn   = xv - LR_X * mval * dEdx;
                    xout[idx]  = xn;
                    tbf16[idx] = f2bf(tanhf(xn));
                }
            }
        }
    }
}

extern "C" void kernel_launch(void* const* d_in, const int* in_sizes, int n_in,
                              void* d_out, int out_size, void* d_ws, size_t ws_size,
                              hipStream_t stream) {
    const float* x_in  = (const float*)d_in[0];
    const float* w_in  = (const float*)d_in[1];
    const int*   mask  = (const int*)d_in[2];
    float*       xbuf  = (float*)d_out;          // state lives in d_out

    uint8_t* ws = (uint8_t*)d_ws;
    // ws layout (55.1 MiB total):
    ushort_t* w_b  = (ushort_t*)(ws);                    // 3328x4096 bf16 = 26 MiB
    ushort_t* wt_b = (ushort_t*)(ws + 27262976);         // 3328x3328 bf16 = 21.1 MiB
    ushort_t* t_b  = (ushort_t*)(ws + 49414144);         // 256x4096 bf16 = 2 MiB
    ushort_t* e_b  = (ushort_t*)(ws + 51511296);         // 256x4096 bf16 = 2 MiB
    float*    e_f  = (float*)   (ws + 53608448);         // 256x4096 f32  = 4 MiB
    // end @ 57802752 bytes

    convert_w<<<dim3(N_DIM / 32, N_LIVE / 32), 256, 0, stream>>>(w_in, w_b, wt_b);
    init_x<<<dim3((B_DIM * N_DIM) / 256), 256, 0, stream>>>(x_in, xbuf, t_b);

    for (int t = 0; t < T_STEPS; ++t) {
        // GEMM1: mu over live cols; A = tanh(x) [k: 0..4096), B = w_b
        gemm_step<1, N_DIM, 0, N_DIM / BK>
            <<<dim3(N_LIVE / BN, B_DIM / BM), 256, 0, stream>>>(
            t_b, w_b, xbuf, nullptr, nullptr, e_f, e_b, nullptr, mask);
        // GEMM2: g over live cols; A = e [k: 768..4096), B = wt_b
        gemm_step<2, N_LIVE, N0, N_LIVE / BK>
            <<<dim3(N_LIVE / BN, B_DIM / BM), 256, 0, stream>>>(
            e_b, wt_b, xbuf, xbuf, e_f, nullptr, nullptr, t_b, mask);
    }
}

// Round 7
// 2506.177 us; speedup vs baseline: 2.7886x; 1.1519x over previous
//
#include <hip/hip_runtime.h>
#include <stdint.h>
#include <stddef.h>

// ---------------------------------------------------------------------------
// PCgraph: T=32 steps of
//   mu = tanh(x) @ w^T ; e = (x-mu)*m ; g = e @ w ;
//   x = x - 0.1*m*(e - (1-tanh(x)^2)*g)
// bf16 MFMA 16x16x32, fp32 accum. x state in d_out (fp32).
// Round 7: SPLIT-K x4 (grid 208 -> 832, ~3.25 blocks/CU). Round-6 analysis:
// per-CU fill rate ~9 B/cyc with 1 block/CU (grid 208) -- the vmcnt(0) drain
// has no co-resident block to overlap with. m97 evidence: same structure at
// ~3 blocks/CU sustains ~52 B/cyc/CU. Epilogues fused via fp32 atomicAdd:
//   e_f pre-set to x; GEMM1 adds -mu_partial  -> e_f = x-mu
//   cvt1: e=m*e_f -> e_b bf16, scale=lr*m*(1-th^2), x -= lr*e
//   GEMM2 adds scale*g_partial into x directly; cvt2: t_b=tanh(x), e_f=x
// GEMM core unchanged from round 2 (BK=64, 32 KB LDS, 44 VGPR, no spill).
// ws 57.25 MiB < proven-safe 57.8 (round-1 failure was OOB ws writes).
// ---------------------------------------------------------------------------

#define N_DIM 4096
#define B_DIM 256
#define T_STEPS 32
#define LR_X 0.1f
#define N0 768                      // first live column (aligned down from 784)
#define N_LIVE 3328                 // 4096 - 768 = 52*64
#define KSPLIT 4

#define BM 64
#define BN 64
#define BK 64

typedef unsigned short ushort_t;
using bf16x8 = __attribute__((ext_vector_type(8))) __bf16;
using f32x4  = __attribute__((ext_vector_type(4))) float;

__device__ __forceinline__ ushort_t f2bf(float f) {
    union { float f; unsigned int u; } v; v.f = f;
    unsigned int r = v.u + 0x7fffu + ((v.u >> 16) & 1u);   // RNE
    return (ushort_t)(r >> 16);
}

__device__ __forceinline__ void async_copy16(const ushort_t* g, ushort_t* l) {
    __builtin_amdgcn_global_load_lds(
        (__attribute__((address_space(1))) void*)(g),
        (__attribute__((address_space(3))) void*)(l),
        16, 0, 0);
}

// --- w fp32 -> w_b bf16 [3328 x 4096] (rows 768..4095 of w)
//             + wt_b bf16 [3328 x 3328] (wt_b[n-768][k-768] = w[k][n]) --------
__global__ void convert_w(const float* __restrict__ w,
                          ushort_t* __restrict__ wb,
                          ushort_t* __restrict__ wtb) {
    __shared__ float tile[32][33];
    const int tx  = threadIdx.x & 31;
    const int ty  = threadIdx.x >> 5;            // 0..7
    const int bx  = blockIdx.x;                  // col tile over [0,4096)
    const int by  = blockIdx.y;                  // row tile over [768,4096)
#pragma unroll
    for (int rr = 0; rr < 32; rr += 8) {
        int rloc = by * 32 + rr + ty;            // row in w_b
        int c    = bx * 32 + tx;
        float v = w[(size_t)(N0 + rloc) * N_DIM + c];
        wb[(size_t)rloc * N_DIM + c] = f2bf(v);
        tile[rr + ty][tx] = v;
    }
    __syncthreads();
    if (bx >= N0 / 32) {                         // cols >= 768 also go to wt_b
#pragma unroll
        for (int rr = 0; rr < 32; rr += 8) {
            int r = bx * 32 - N0 + rr + ty;      // wt row = c_w - 768
            int c = by * 32 + tx;                // wt col = r_w - 768
            wtb[(size_t)r * N_LIVE + c] = f2bf(tile[tx][rr + ty]);
        }
    }
}

// --- init: x -> d_out, t_b = tanh(x) bf16 (full), e_f = x (live cols) -------
__global__ void init_x(const float* __restrict__ xin,
                       float* __restrict__ xout,
                       ushort_t* __restrict__ tb,
                       float* __restrict__ ef) {
    int i = blockIdx.x * 256 + threadIdx.x;
    int b = i >> 12, c = i & 4095;
    float v = xin[i];
    xout[i] = v;
    tb[i]   = f2bf(tanhf(v));
    if (c >= N0) ef[(size_t)b * N_LIVE + (c - N0)] = v;
}

// --- cvt1 (after GEMM1): e_f holds x-mu at live cols ------------------------
__global__ void cvt1(float* xbuf,
                     const float* __restrict__ ef,
                     ushort_t* __restrict__ eb,
                     float* __restrict__ scf,
                     const int* __restrict__ mask) {
    const int b  = blockIdx.y;
    const int nl = blockIdx.x * 256 + threadIdx.x;
    const size_t il = (size_t)b * N_LIVE + nl;
    const size_t ix = (size_t)b * N_DIM + N0 + nl;
    float x    = xbuf[ix];
    float e    = ef[il] * (float)mask[N0 + nl];
    float th   = tanhf(x);
    eb[il]  = f2bf(e);
    scf[il] = LR_X * (float)mask[N0 + nl] * (1.0f - th * th);
    xbuf[ix] = x - LR_X * e;        // GEMM2 atomically adds +lr*m*(1-th^2)*g
}

// --- cvt2 (after GEMM2): x_new complete; refresh t_b and re-seed e_f --------
__global__ void cvt2(const float* __restrict__ xbuf,
                     ushort_t* __restrict__ tb,
                     float* __restrict__ ef) {
    const int b  = blockIdx.y;
    const int nl = blockIdx.x * 256 + threadIdx.x;
    const size_t ix = (size_t)b * N_DIM + N0 + nl;
    float xn = xbuf[ix];
    tb[ix] = f2bf(tanhf(xn));
    ef[(size_t)b * N_LIVE + nl] = xn;   // next GEMM1 target: e_f = x
}

// --- split-K GEMM, atomic epilogue ------------------------------------------
// partial C[m][nloc] = sum over k-slice of A[m][k]*B[nloc][k]; A,B stride = STRIDE.
// PHASE 1: atomicAdd(e_f[m][nloc], -v)          (e_f pre-set to x)
// PHASE 2: atomicAdd(x[m][N0+nloc], scale[m][nloc]*v)
template <int PHASE, int STRIDE, int KITERS>
__global__ __launch_bounds__(256) void gemm_split(
    const ushort_t* __restrict__ Amat,
    const ushort_t* __restrict__ Bmat,
    float* __restrict__ accum_out,
    const float* __restrict__ scale) {
    // Fragment-order LDS (round-2 core): sub-tile s = 512 elem; staging lane L
    // writes exactly the 16B compute-lane L reads -> conflict-free.
    __shared__ __align__(16) ushort_t As[2][BM * BK];
    __shared__ __align__(16) ushort_t Bs[2][BN * BK];

    const int tid    = threadIdx.x;
    const int lane   = tid & 63;
    const int wid    = tid >> 6;       // 0..3
    const int wave_m = wid >> 1;       // 0..1
    const int wave_n = wid & 1;        // 0..1
    const int n0loc  = blockIdx.x * BN;
    const int m0     = blockIdx.y * BM;
    const int kbase  = blockIdx.z * (KITERS * BK);

    const int l15  = lane & 15;
    const int quad = lane >> 4;        // 0..3

    auto stage = [&](int buf, int kt) {
        const int k0 = kbase + kt * BK;
#pragma unroll
        for (int u = 0; u < 2; ++u) {
            const int s    = wid * 2 + u;          // sub-tile id 0..7
            const int row  = (s >> 1) * 16 + l15;  // m (or n) within tile
            const int kk   = k0 + (s & 1) * 32 + (quad << 3);
            async_copy16(Amat + (size_t)(m0 + row) * STRIDE + kk,
                         &As[buf][s * 512 + lane * 8]);
            async_copy16(Bmat + (size_t)(n0loc + row) * STRIDE + kk,
                         &Bs[buf][s * 512 + lane * 8]);
        }
    };

    f32x4 acc[2][2] = {};

    auto compute = [&](int buf) {
#pragma unroll
        for (int ks = 0; ks < 2; ++ks) {
            bf16x8 a[2], b[2];
#pragma unroll
            for (int i = 0; i < 2; ++i) {
                const int asub = (wave_m * 2 + i) * 2 + ks;
                const int bsub = (wave_n * 2 + i) * 2 + ks;
                a[i] = *(const bf16x8*)(&As[buf][asub * 512 + lane * 8]);
                b[i] = *(const bf16x8*)(&Bs[buf][bsub * 512 + lane * 8]);
            }
#pragma unroll
            for (int i = 0; i < 2; ++i)
#pragma unroll
                for (int j = 0; j < 2; ++j)
                    acc[i][j] = __builtin_amdgcn_mfma_f32_16x16x32_bf16(
                        a[i], b[j], acc[i][j], 0, 0, 0);
        }
    };

    stage(0, 0);
    __syncthreads();
    for (int kt = 0; kt < KITERS; ++kt) {
        if (kt + 1 < KITERS) stage((kt + 1) & 1, kt + 1);
        compute(kt & 1);
        __syncthreads();
    }

    // Epilogue. C/D layout (verified m89/m91): col = lane&15, row = quad*4+reg
#pragma unroll
    for (int j = 0; j < 2; ++j) {
        const int nl = n0loc + wave_n * 32 + j * 16 + l15;
#pragma unroll
        for (int i = 0; i < 2; ++i) {
#pragma unroll
            for (int r = 0; r < 4; ++r) {
                const int m = m0 + wave_m * 32 + i * 16 + quad * 4 + r;
                const float v = acc[i][j][r];
                if (PHASE == 1) {
                    atomicAdd(&accum_out[(size_t)m * N_LIVE + nl], -v);
                } else {
                    const float s = scale[(size_t)m * N_LIVE + nl];
                    atomicAdd(&accum_out[(size_t)m * N_DIM + N0 + nl], s * v);
                }
            }
        }
    }
}

extern "C" void kernel_launch(void* const* d_in, const int* in_sizes, int n_in,
                              void* d_out, int out_size, void* d_ws, size_t ws_size,
                              hipStream_t stream) {
    const float* x_in  = (const float*)d_in[0];
    const float* w_in  = (const float*)d_in[1];
    const int*   mask  = (const int*)d_in[2];
    float*       xbuf  = (float*)d_out;          // state lives in d_out

    uint8_t* ws = (uint8_t*)d_ws;
    // ws layout (57.25 MiB total):
    ushort_t* w_b  = (ushort_t*)(ws);                    // 3328x4096 bf16 = 26 MiB
    ushort_t* wt_b = (ushort_t*)(ws + 27262976);         // 3328x3328 bf16
    ushort_t* t_b  = (ushort_t*)(ws + 49414144);         // 256x4096 bf16
    ushort_t* e_b  = (ushort_t*)(ws + 51511296);         // 256x3328 bf16
    float*    e_f  = (float*)   (ws + 53215232);         // 256x3328 f32
    float*    sc_f = (float*)   (ws + 56623104);         // 256x3328 f32
    // end @ 60030976 bytes

    convert_w<<<dim3(N_DIM / 32, N_LIVE / 32), 256, 0, stream>>>(w_in, w_b, wt_b);
    init_x<<<dim3((B_DIM * N_DIM) / 256), 256, 0, stream>>>(x_in, xbuf, t_b, e_f);

    const dim3 ggrid(N_LIVE / BN, B_DIM / BM, KSPLIT);
    const dim3 cgrid(N_LIVE / 256, B_DIM);
    for (int t = 0; t < T_STEPS; ++t) {
        // GEMM1: e_f (=x) -= mu_partial ; A = t_b (k 0..4096), B = w_b
        gemm_split<1, N_DIM, N_DIM / BK / KSPLIT>
            <<<ggrid, 256, 0, stream>>>(t_b, w_b, e_f, nullptr);
        cvt1<<<cgrid, 256, 0, stream>>>(xbuf, e_f, e_b, sc_f, mask);
        // GEMM2: x += scale * g_partial ; A = e_b, B = wt_b (k 0..3328 local)
        gemm_split<2, N_LIVE, N_LIVE / BK / KSPLIT>
            <<<ggrid, 256, 0, stream>>>(e_b, wt_b, xbuf, sc_f);
        cvt2<<<cgrid, 256, 0, stream>>>(xbuf, t_b, e_f);
    }
}

// Round 8
// 2212.566 us; speedup vs baseline: 3.1587x; 1.1327x over previous
//
#include <hip/hip_runtime.h>
#include <stdint.h>
#include <stddef.h>

// ---------------------------------------------------------------------------
// PCgraph: T=32 steps of
//   mu = tanh(x) @ w^T ; e = (x-mu)*m ; g = e @ w ;
//   x = x - 0.1*m*(e - (1-tanh(x)^2)*g)
// bf16 MFMA 16x16x32, fp32 accum. x state in d_out (fp32).
// Round 8: split-K x4 with PER-SLICE PARTIAL BUFFERS (bf16) + reduction in
// the cvt kernels. Round 7's fp32 atomicAdd epilogue serialized (rocprof
// showed a 20.5 ms gemm_split at MfmaUtil 0.6; graph step ~77 us vs ~20
// expected). No atomics anywhere now. x-update deferred to cvt2 (rereads
// e_b) so e_f/sc_f buffers vanish -> ws end exactly at the proven-safe
// 60,030,976 bytes. GEMM core unchanged from rounds 2/7.
// ---------------------------------------------------------------------------

#define N_DIM 4096
#define B_DIM 256
#define T_STEPS 32
#define LR_X 0.1f
#define N0 768                      // first live column (aligned down from 784)
#define N_LIVE 3328                 // 4096 - 768 = 52*64
#define KSPLIT 4

#define BM 64
#define BN 64
#define BK 64

typedef unsigned short ushort_t;
using bf16x8 = __attribute__((ext_vector_type(8))) __bf16;
using f32x4  = __attribute__((ext_vector_type(4))) float;

__device__ __forceinline__ ushort_t f2bf(float f) {
    union { float f; unsigned int u; } v; v.f = f;
    unsigned int r = v.u + 0x7fffu + ((v.u >> 16) & 1u);   // RNE
    return (ushort_t)(r >> 16);
}
__device__ __forceinline__ float bf2f(ushort_t h) {
    union { unsigned int u; float f; } v; v.u = ((unsigned int)h) << 16;
    return v.f;
}

__device__ __forceinline__ void async_copy16(const ushort_t* g, ushort_t* l) {
    __builtin_amdgcn_global_load_lds(
        (__attribute__((address_space(1))) void*)(g),
        (__attribute__((address_space(3))) void*)(l),
        16, 0, 0);
}

// --- w fp32 -> w_b bf16 [3328 x 4096] (rows 768..4095 of w)
//             + wt_b bf16 [3328 x 3328] (wt_b[n-768][k-768] = w[k][n]) --------
__global__ void convert_w(const float* __restrict__ w,
                          ushort_t* __restrict__ wb,
                          ushort_t* __restrict__ wtb) {
    __shared__ float tile[32][33];
    const int tx  = threadIdx.x & 31;
    const int ty  = threadIdx.x >> 5;            // 0..7
    const int bx  = blockIdx.x;                  // col tile over [0,4096)
    const int by  = blockIdx.y;                  // row tile over [768,4096)
#pragma unroll
    for (int rr = 0; rr < 32; rr += 8) {
        int rloc = by * 32 + rr + ty;            // row in w_b
        int c    = bx * 32 + tx;
        float v = w[(size_t)(N0 + rloc) * N_DIM + c];
        wb[(size_t)rloc * N_DIM + c] = f2bf(v);
        tile[rr + ty][tx] = v;
    }
    __syncthreads();
    if (bx >= N0 / 32) {                         // cols >= 768 also go to wt_b
#pragma unroll
        for (int rr = 0; rr < 32; rr += 8) {
            int r = bx * 32 - N0 + rr + ty;      // wt row = c_w - 768
            int c = by * 32 + tx;                // wt col = r_w - 768
            wtb[(size_t)r * N_LIVE + c] = f2bf(tile[tx][rr + ty]);
        }
    }
}

// --- init: x -> d_out, t_b = tanh(x) bf16 (full width) ----------------------
__global__ void init_x(const float* __restrict__ xin,
                       float* __restrict__ xout,
                       ushort_t* __restrict__ tb) {
    int i = blockIdx.x * 256 + threadIdx.x;
    float v = xin[i];
    xout[i] = v;
    tb[i]   = f2bf(tanhf(v));
}

// --- cvt1 (after GEMM1): mu = sum of partials; e_b = (x - mu)*m in bf16 -----
__global__ void cvt1(const float* __restrict__ xbuf,
                     const ushort_t* __restrict__ part,
                     ushort_t* __restrict__ eb,
                     const int* __restrict__ mask) {
    const int b  = blockIdx.y;
    const int nl = blockIdx.x * 256 + threadIdx.x;
    const size_t il = (size_t)b * N_LIVE + nl;
    float mu = 0.0f;
#pragma unroll
    for (int z = 0; z < KSPLIT; ++z)
        mu += bf2f(part[(size_t)z * (B_DIM * N_LIVE) + il]);
    const float x = xbuf[(size_t)b * N_DIM + N0 + nl];
    eb[il] = f2bf((x - mu) * (float)mask[N0 + nl]);
}

// --- cvt2 (after GEMM2): g = sum of partials; full x-update + tanh ---------
__global__ void cvt2(float* __restrict__ xbuf,
                     const ushort_t* __restrict__ part,
                     const ushort_t* __restrict__ eb,
                     ushort_t* __restrict__ tb,
                     const int* __restrict__ mask) {
    const int b  = blockIdx.y;
    const int nl = blockIdx.x * 256 + threadIdx.x;
    const size_t il = (size_t)b * N_LIVE + nl;
    const size_t ix = (size_t)b * N_DIM + N0 + nl;
    float g = 0.0f;
#pragma unroll
    for (int z = 0; z < KSPLIT; ++z)
        g += bf2f(part[(size_t)z * (B_DIM * N_LIVE) + il]);
    const float x  = xbuf[ix];
    const float th = tanhf(x);
    const float e  = bf2f(eb[il]);
    const float m  = (float)mask[N0 + nl];
    const float xn = x - LR_X * m * (e - (1.0f - th * th) * g);
    xbuf[ix] = xn;
    tb[ix]   = f2bf(tanhf(xn));
}

// --- split-K GEMM, bf16 partial-store epilogue ------------------------------
// partial[m][nloc] = sum over k-slice z of A[m][k]*B[nloc][k]; stride STRIDE.
template <int STRIDE, int KITERS>
__global__ __launch_bounds__(256) void gemm_split(
    const ushort_t* __restrict__ Amat,
    const ushort_t* __restrict__ Bmat,
    ushort_t* __restrict__ part) {
    // Fragment-order LDS (round-2 core): sub-tile s = 512 elem; staging lane L
    // writes exactly the 16B compute-lane L reads -> conflict-free.
    __shared__ __align__(16) ushort_t As[2][BM * BK];
    __shared__ __align__(16) ushort_t Bs[2][BN * BK];

    const int tid    = threadIdx.x;
    const int lane   = tid & 63;
    const int wid    = tid >> 6;       // 0..3
    const int wave_m = wid >> 1;       // 0..1
    const int wave_n = wid & 1;        // 0..1
    const int n0loc  = blockIdx.x * BN;
    const int m0     = blockIdx.y * BM;
    const int kbase  = blockIdx.z * (KITERS * BK);
    ushort_t* pout   = part + (size_t)blockIdx.z * (B_DIM * N_LIVE);

    const int l15  = lane & 15;
    const int quad = lane >> 4;        // 0..3

    auto stage = [&](int buf, int kt) {
        const int k0 = kbase + kt * BK;
#pragma unroll
        for (int u = 0; u < 2; ++u) {
            const int s    = wid * 2 + u;          // sub-tile id 0..7
            const int row  = (s >> 1) * 16 + l15;  // m (or n) within tile
            const int kk   = k0 + (s & 1) * 32 + (quad << 3);
            async_copy16(Amat + (size_t)(m0 + row) * STRIDE + kk,
                         &As[buf][s * 512 + lane * 8]);
            async_copy16(Bmat + (size_t)(n0loc + row) * STRIDE + kk,
                         &Bs[buf][s * 512 + lane * 8]);
        }
    };

    f32x4 acc[2][2] = {};

    auto compute = [&](int buf) {
#pragma unroll
        for (int ks = 0; ks < 2; ++ks) {
            bf16x8 a[2], b[2];
#pragma unroll
            for (int i = 0; i < 2; ++i) {
                const int asub = (wave_m * 2 + i) * 2 + ks;
                const int bsub = (wave_n * 2 + i) * 2 + ks;
                a[i] = *(const bf16x8*)(&As[buf][asub * 512 + lane * 8]);
                b[i] = *(const bf16x8*)(&Bs[buf][bsub * 512 + lane * 8]);
            }
#pragma unroll
            for (int i = 0; i < 2; ++i)
#pragma unroll
                for (int j = 0; j < 2; ++j)
                    acc[i][j] = __builtin_amdgcn_mfma_f32_16x16x32_bf16(
                        a[i], b[j], acc[i][j], 0, 0, 0);
        }
    };

    stage(0, 0);
    __syncthreads();
    for (int kt = 0; kt < KITERS; ++kt) {
        if (kt + 1 < KITERS) stage((kt + 1) & 1, kt + 1);
        compute(kt & 1);
        __syncthreads();
    }

    // Epilogue: plain bf16 partial stores (no atomics).
    // C/D layout (verified m89/m91): col = lane&15, row = quad*4+reg
#pragma unroll
    for (int j = 0; j < 2; ++j) {
        const int nl = n0loc + wave_n * 32 + j * 16 + l15;
#pragma unroll
        for (int i = 0; i < 2; ++i) {
#pragma unroll
            for (int r = 0; r < 4; ++r) {
                const int m = m0 + wave_m * 32 + i * 16 + quad * 4 + r;
                pout[(size_t)m * N_LIVE + nl] = f2bf(acc[i][j][r]);
            }
        }
    }
}

extern "C" void kernel_launch(void* const* d_in, const int* in_sizes, int n_in,
                              void* d_out, int out_size, void* d_ws, size_t ws_size,
                              hipStream_t stream) {
    const float* x_in  = (const float*)d_in[0];
    const float* w_in  = (const float*)d_in[1];
    const int*   mask  = (const int*)d_in[2];
    float*       xbuf  = (float*)d_out;          // state lives in d_out

    uint8_t* ws = (uint8_t*)d_ws;
    // ws layout (end @ 60,030,976 bytes -- exactly the round-7 proven-safe end):
    ushort_t* w_b  = (ushort_t*)(ws);                    // 3328x4096 bf16 = 27,262,976
    ushort_t* wt_b = (ushort_t*)(ws + 27262976);         // 3328x3328 bf16 = 22,151,168
    ushort_t* t_b  = (ushort_t*)(ws + 49414144);         // 256x4096 bf16  =  2,097,152
    ushort_t* e_b  = (ushort_t*)(ws + 51511296);         // 256x3328 bf16  =  1,703,936
    ushort_t* part = (ushort_t*)(ws + 53215232);         // 4x256x3328 bf16=  6,815,744

    convert_w<<<dim3(N_DIM / 32, N_LIVE / 32), 256, 0, stream>>>(w_in, w_b, wt_b);
    init_x<<<dim3((B_DIM * N_DIM) / 256), 256, 0, stream>>>(x_in, xbuf, t_b);

    const dim3 ggrid(N_LIVE / BN, B_DIM / BM, KSPLIT);
    const dim3 cgrid(N_LIVE / 256, B_DIM);
    for (int t = 0; t < T_STEPS; ++t) {
        // GEMM1: part[z] = mu partial ; A = t_b (k 0..4096), B = w_b
        gemm_split<N_DIM, N_DIM / BK / KSPLIT>
            <<<ggrid, 256, 0, stream>>>(t_b, w_b, part);
        cvt1<<<cgrid, 256, 0, stream>>>(xbuf, part, e_b, mask);
        // GEMM2: part[z] = g partial ; A = e_b, B = wt_b (k-local 0..3328)
        gemm_split<N_LIVE, N_LIVE / BK / KSPLIT>
            <<<ggrid, 256, 0, stream>>>(e_b, wt_b, part);
        cvt2<<<cgrid, 256, 0, stream>>>(xbuf, part, e_b, t_b, mask);
    }
}

// Round 9
// 1414.801 us; speedup vs baseline: 4.9398x; 1.5639x over previous
//
#include <hip/hip_runtime.h>
#include <stdint.h>
#include <stddef.h>

// ---------------------------------------------------------------------------
// PCgraph: T=32 steps of
//   mu = tanh(x) @ w^T ; e = (x-mu)*m ; g = e @ w ;
//   x = x - 0.1*m*(e - (1-tanh(x)^2)*g)
// bf16 MFMA 16x16x32, fp32 accum. x state in d_out (fp32).
// Round 9: PACKED OPERAND LAYOUT. Rounds 6-8 showed the global_load_lds fill
// rate stuck at ~10-12 B/cyc/CU regardless of MLP depth (r6) or co-residency
// (r7/r8 at 13 waves/CU = m97's). Remaining difference vs m97 (44 B/cyc/CU):
// our staging instructions gathered 16 scattered 64B segments (fragment
// order over row-major tiles); m97's are lane-contiguous 1KB. Fix: store
// w, w^T, tanh(x), e in fragment-order tile-chunk layout [tile][kchunk][4096]
// so every async_copy16 wave-instruction reads 1KB linear. Producers all
// owned: pack_w (once), pack_t_init (once), cvt1/cvt2 (scattered 2B writes,
// 1.7 MB). GEMM core/split-K/partials unchanged from round 8.
// ws end @ 60,030,976 bytes (proven safe; round-1 failure was OOB ws).
// ---------------------------------------------------------------------------

#define N_DIM 4096
#define B_DIM 256
#define T_STEPS 32
#define LR_X 0.1f
#define N0 768                      // first live column (aligned down from 784)
#define N_LIVE 3328                 // 4096 - 768 = 52*64
#define KSPLIT 4

#define BM 64
#define BN 64
#define BK 64
#define NCH1 64                     // k-chunks in GEMM1 (k over 4096)
#define NCH2 52                     // k-chunks in GEMM2 (k over 3328)

typedef unsigned short ushort_t;
using bf16x8 = __attribute__((ext_vector_type(8))) __bf16;
using f32x4  = __attribute__((ext_vector_type(4))) float;

__device__ __forceinline__ ushort_t f2bf(float f) {
    union { float f; unsigned int u; } v; v.f = f;
    unsigned int r = v.u + 0x7fffu + ((v.u >> 16) & 1u);   // RNE
    return (ushort_t)(r >> 16);
}
__device__ __forceinline__ float bf2f(ushort_t h) {
    union { unsigned int u; float f; } v; v.u = ((unsigned int)h) << 16;
    return v.f;
}

// fragment-order index of element (r, c) inside a 64x64 tile-chunk
// (matches the LDS layout the MFMA fragments read; verified rounds 0-8)
__device__ __forceinline__ int pkidx(int r, int c) {
    const int s = ((r >> 4) << 1) | ((c >> 5) & 1);
    return s * 512 + (r & 15) * 8 + (((c >> 3) & 3) << 7) + (c & 7);
}

__device__ __forceinline__ void async_copy16(const ushort_t* g, ushort_t* l) {
    __builtin_amdgcn_global_load_lds(
        (__attribute__((address_space(1))) void*)(g),
        (__attribute__((address_space(3))) void*)(l),
        16, 0, 0);
}

// --- pack w -> w_pk [52 ntile][64 chunk][4096]  (B of GEMM1: rows 768..4095)
//            -> wt_pk [52 ntile][52 chunk][4096] (B of GEMM2: w^T, live range)
__global__ __launch_bounds__(256) void pack_w(const float* __restrict__ w,
                                              ushort_t* __restrict__ wpk,
                                              ushort_t* __restrict__ wtpk) {
    __shared__ float tile[64][68];
    const int tid = threadIdx.x;
    const int bid = blockIdx.x;
    int row0, col0; ushort_t* dst; bool tr;
    if (bid < 52 * 64) {
        tr   = false;
        dst  = wpk + (size_t)bid * 4096;
        row0 = N0 + (bid >> 6) * 64;      // B-row (n) block
        col0 = (bid & 63) * 64;           // k block
    } else {
        const int b2 = bid - 52 * 64;
        tr   = true;
        dst  = wtpk + (size_t)b2 * 4096;
        const int ntile = b2 / 52, chunk = b2 - ntile * 52;
        row0 = N0 + chunk * 64;           // w-row  = k block (live)
        col0 = N0 + ntile * 64;           // w-col  = n block (live)
    }
    const int rr = tid >> 2, c0 = (tid & 3) * 16;
    const float* src = w + (size_t)(row0 + rr) * N_DIM + col0 + c0;
#pragma unroll
    for (int i = 0; i < 16; i += 4)
        *(float4*)&tile[rr][c0 + i] = *(const float4*)(src + i);
    __syncthreads();
    ushort_t loc[16];
#pragma unroll
    for (int i = 0; i < 16; ++i) {
        const int p = tid * 16 + i;
        const int s = p >> 9, e = p & 511;
        const int r = ((s >> 1) << 4) | ((e >> 3) & 15);
        const int c = ((s & 1) << 5) | (((e >> 7) & 3) << 3) | (e & 7);
        loc[i] = f2bf(tr ? tile[c][r] : tile[r][c]);
    }
    *(uint4*)&dst[tid * 16]     = *(uint4*)&loc[0];
    *(uint4*)&dst[tid * 16 + 8] = *(uint4*)&loc[8];
}

// --- init: x -> d_out (row-major) and t_pk [4 mtile][64 chunk][4096] --------
__global__ __launch_bounds__(256) void pack_t_init(const float* __restrict__ xin,
                                                   float* __restrict__ xout,
                                                   ushort_t* __restrict__ tpk) {
    __shared__ float tile[64][68];
    const int tid  = threadIdx.x;
    const int bid  = blockIdx.x;          // mtile*64 + chunk
    const int row0 = (bid >> 6) * 64;
    const int col0 = (bid & 63) * 64;
    const int rr = tid >> 2, c0 = (tid & 3) * 16;
    const size_t sidx = (size_t)(row0 + rr) * N_DIM + col0 + c0;
#pragma unroll
    for (int i = 0; i < 16; i += 4) {
        float4 v = *(const float4*)(xin + sidx + i);
        *(float4*)(xout + sidx + i) = v;
        tile[rr][c0 + i + 0] = tanhf(v.x);
        tile[rr][c0 + i + 1] = tanhf(v.y);
        tile[rr][c0 + i + 2] = tanhf(v.z);
        tile[rr][c0 + i + 3] = tanhf(v.w);
    }
    __syncthreads();
    ushort_t loc[16];
    ushort_t* dst = tpk + (size_t)bid * 4096;
#pragma unroll
    for (int i = 0; i < 16; ++i) {
        const int p = tid * 16 + i;
        const int s = p >> 9, e = p & 511;
        const int r = ((s >> 1) << 4) | ((e >> 3) & 15);
        const int c = ((s & 1) << 5) | (((e >> 7) & 3) << 3) | (e & 7);
        loc[i] = f2bf(tile[r][c]);
    }
    *(uint4*)&dst[tid * 16]     = *(uint4*)&loc[0];
    *(uint4*)&dst[tid * 16 + 8] = *(uint4*)&loc[8];
}

// --- cvt1 (after GEMM1): mu = sum partials; e -> e_pk (packed, GEMM2 A) -----
__global__ void cvt1(const float* __restrict__ xbuf,
                     const ushort_t* __restrict__ part,
                     ushort_t* __restrict__ epk,
                     const int* __restrict__ mask) {
    const int b  = blockIdx.y;
    const int nl = blockIdx.x * 256 + threadIdx.x;
    const size_t il = (size_t)b * N_LIVE + nl;
    float mu = 0.0f;
#pragma unroll
    for (int z = 0; z < KSPLIT; ++z)
        mu += bf2f(part[(size_t)z * (B_DIM * N_LIVE) + il]);
    const float x = xbuf[(size_t)b * N_DIM + N0 + nl];
    const float e = (x - mu) * (float)mask[N0 + nl];
    epk[((size_t)((b >> 6) * NCH2 + (nl >> 6))) * 4096 + pkidx(b & 63, nl & 63)]
        = f2bf(e);
}

// --- cvt2 (after GEMM2): g = sum partials; x update; refresh t_pk -----------
__global__ void cvt2(float* __restrict__ xbuf,
                     const ushort_t* __restrict__ part,
                     const ushort_t* __restrict__ epk,
                     ushort_t* __restrict__ tpk,
                     const int* __restrict__ mask) {
    const int b  = blockIdx.y;
    const int nl = blockIdx.x * 256 + threadIdx.x;
    const size_t ix = (size_t)b * N_DIM + N0 + nl;
    float g = 0.0f;
#pragma unroll
    for (int z = 0; z < KSPLIT; ++z)
        g += bf2f(part[(size_t)z * (B_DIM * N_LIVE) + (size_t)b * N_LIVE + nl]);
    const float x  = xbuf[ix];
    const float th = tanhf(x);
    const float e  = bf2f(epk[((size_t)((b >> 6) * NCH2 + (nl >> 6))) * 4096
                              + pkidx(b & 63, nl & 63)]);
    const float m  = (float)mask[N0 + nl];
    const float xn = x - LR_X * m * (e - (1.0f - th * th) * g);
    xbuf[ix] = xn;
    const int k = N0 + nl;
    tpk[((size_t)((b >> 6) * NCH1 + (k >> 6))) * 4096 + pkidx(b & 63, k & 63)]
        = f2bf(tanhf(xn));
}

// --- split-K GEMM over packed operands --------------------------------------
// Apk: [4 mtile][NCH][4096], Bpk: [52 ntile][NCH][4096]; every async_copy16
// wave-instruction reads 1KB linear; a block's stream is KITERS*8KB linear.
template <int NCH, int KITERS>
__global__ __launch_bounds__(256) void gemm_split(
    const ushort_t* __restrict__ Apk,
    const ushort_t* __restrict__ Bpk,
    ushort_t* __restrict__ part) {
    __shared__ __align__(16) ushort_t As[2][BM * BK];
    __shared__ __align__(16) ushort_t Bs[2][BN * BK];

    const int tid    = threadIdx.x;
    const int lane   = tid & 63;
    const int wid    = tid >> 6;       // 0..3
    const int wave_m = wid >> 1;       // 0..1
    const int wave_n = wid & 1;        // 0..1
    const int ntile  = blockIdx.x;
    const int mtile  = blockIdx.y;
    const int chbase = blockIdx.z * KITERS;
    ushort_t* pout   = part + (size_t)blockIdx.z * (B_DIM * N_LIVE);

    const int l15  = lane & 15;
    const int quad = lane >> 4;        // 0..3

    const ushort_t* Abase = Apk + ((size_t)mtile * NCH + chbase) * 4096;
    const ushort_t* Bbase = Bpk + ((size_t)ntile * NCH + chbase) * 4096;

    auto stage = [&](int buf, int kt) {
        const size_t co = (size_t)kt * 4096;
#pragma unroll
        for (int u = 0; u < 2; ++u) {
            const int off = (wid * 2 + u) * 512 + lane * 8;
            async_copy16(Abase + co + off, &As[buf][off]);
            async_copy16(Bbase + co + off, &Bs[buf][off]);
        }
    };

    f32x4 acc[2][2] = {};

    auto compute = [&](int buf) {
#pragma unroll
        for (int ks = 0; ks < 2; ++ks) {
            bf16x8 a[2], b[2];
#pragma unroll
            for (int i = 0; i < 2; ++i) {
                const int asub = (wave_m * 2 + i) * 2 + ks;
                const int bsub = (wave_n * 2 + i) * 2 + ks;
                a[i] = *(const bf16x8*)(&As[buf][asub * 512 + lane * 8]);
                b[i] = *(const bf16x8*)(&Bs[buf][bsub * 512 + lane * 8]);
            }
#pragma unroll
            for (int i = 0; i < 2; ++i)
#pragma unroll
                for (int j = 0; j < 2; ++j)
                    acc[i][j] = __builtin_amdgcn_mfma_f32_16x16x32_bf16(
                        a[i], b[j], acc[i][j], 0, 0, 0);
        }
    };

    stage(0, 0);
    __syncthreads();
    for (int kt = 0; kt < KITERS; ++kt) {
        if (kt + 1 < KITERS) stage((kt + 1) & 1, kt + 1);
        compute(kt & 1);
        __syncthreads();
    }

    // Epilogue: plain bf16 partial stores (row-major partials).
    // C/D layout (verified m89/m91): col = lane&15, row = quad*4+reg
#pragma unroll
    for (int j = 0; j < 2; ++j) {
        const int nl = ntile * BN + wave_n * 32 + j * 16 + l15;
#pragma unroll
        for (int i = 0; i < 2; ++i) {
#pragma unroll
            for (int r = 0; r < 4; ++r) {
                const int m = mtile * BM + wave_m * 32 + i * 16 + quad * 4 + r;
                pout[(size_t)m * N_LIVE + nl] = f2bf(acc[i][j][r]);
            }
        }
    }
}

extern "C" void kernel_launch(void* const* d_in, const int* in_sizes, int n_in,
                              void* d_out, int out_size, void* d_ws, size_t ws_size,
                              hipStream_t stream) {
    const float* x_in  = (const float*)d_in[0];
    const float* w_in  = (const float*)d_in[1];
    const int*   mask  = (const int*)d_in[2];
    float*       xbuf  = (float*)d_out;          // state lives in d_out

    uint8_t* ws = (uint8_t*)d_ws;
    // ws layout (end @ 60,030,976 bytes -- proven-safe since round 7):
    ushort_t* w_pk  = (ushort_t*)(ws);                   // 52*64*4096*2 = 27,262,976
    ushort_t* wt_pk = (ushort_t*)(ws + 27262976);        // 52*52*4096*2 = 22,151,168
    ushort_t* t_pk  = (ushort_t*)(ws + 49414144);        //  4*64*4096*2 =  2,097,152
    ushort_t* e_pk  = (ushort_t*)(ws + 51511296);        //  4*52*4096*2 =  1,703,936
    ushort_t* part  = (ushort_t*)(ws + 53215232);        // 4*256*3328*2 =  6,815,744

    pack_w<<<dim3(52 * 64 + 52 * 52), 256, 0, stream>>>(w_in, w_pk, wt_pk);
    pack_t_init<<<dim3(4 * 64), 256, 0, stream>>>(x_in, xbuf, t_pk);

    const dim3 ggrid(N_LIVE / BN, B_DIM / BM, KSPLIT);
    const dim3 cgrid(N_LIVE / 256, B_DIM);
    for (int t = 0; t < T_STEPS; ++t) {
        // GEMM1: part[z] = mu partial ; A = t_pk (64 chunks), B = w_pk
        gemm_split<NCH1, NCH1 / KSPLIT>
            <<<ggrid, 256, 0, stream>>>(t_pk, w_pk, part);
        cvt1<<<cgrid, 256, 0, stream>>>(xbuf, part, e_pk, mask);
        // GEMM2: part[z] = g partial ; A = e_pk (52 chunks), B = wt_pk
        gemm_split<NCH2, NCH2 / KSPLIT>
            <<<ggrid, 256, 0, stream>>>(e_pk, wt_pk, part);
        cvt2<<<cgrid, 256, 0, stream>>>(xbuf, part, e_pk, t_pk, mask);
    }
}